// Round 2
// baseline (4792.022 us; speedup 1.0000x reference)
//
#include <hip/hip_runtime.h>

// Problem:
// x:       (128, 3, 4, 32, 32) fp32
// tensors: (3, 8, 31, 31, 4,4,4,4, 6) fp32 -> W[c,p,site, m=ijkl(256), o(6)]
// bias:    (8, 31, 31, 6) fp32
// out:     (128, 8, 6, 31, 31) fp32 = out[f*961 + site], f = n*48 + p*6 + o
//
// Phase 1: one block per site, 384 threads. Per c: stage AB/CD (rank-1 factors),
//          stream W in 64-m chunks through LDS, 4n x 4po register tile.
//          Results -> ws[site][f] with float4 stores (full-line coverage).
// Phase 2: tiled transpose ws(961 x 6144) -> out(6144 x 961) + bias.
// LDS phase 1: 2*128*16 + 64*48 floats = 28672 B -> 4 blocks/CU at 84 VGPR.

#define WS_ELEMS (961u * 6144u)

template <bool TO_WS>
__global__ __launch_bounds__(384, 6)
void ttn_conv_fp32(const float* __restrict__ x,
                   const float* __restrict__ tensors,
                   const float* __restrict__ bias,
                   float* __restrict__ dst) {
  __shared__ float sAB[128 * 16];
  __shared__ float sCD[128 * 16];
  __shared__ float sW[64 * 48];

  const int site = blockIdx.x;
  const int xx = site / 31;
  const int yy = site - xx * 31;
  const int t = threadIdx.x;

  const int pog = t % 12;   // po = pog*4 + q, q in 0..3
  const int ng  = t / 12;   // n  = ng*4 + r,  r in 0..3

  float acc[4][4] = {};

  for (int c = 0; c < 3; ++c) {
    __syncthreads();   // previous MAC done before overwriting sAB/sCD
    // ---- stage AB / CD for this c: roles over 384 threads ----
    if (t < 256) {
      const int role = t >> 7;          // 0: ab, 1: cd
      const int n = t & 127;
      const float* xp = x + ((size_t)n * 3 + c) * 4096 + xx * 32 + yy;
      float u[4], v[4];
#pragma unroll
      for (int i = 0; i < 4; ++i) {
        const float* r0 = xp + i * 1024;
        u[i] = (role == 0) ? r0[0]  : r0[1];    // a_i  or c_i
        v[i] = (role == 0) ? r0[32] : r0[33];   // b_j  or d_j
      }
      float* dstl = (role == 0 ? sAB : sCD) + n * 16;
#pragma unroll
      for (int i = 0; i < 4; ++i)
#pragma unroll
        for (int j = 0; j < 4; ++j)
          dstl[i * 4 + j] = u[i] * v[j];
    }

    for (int mb = 0; mb < 4; ++mb) {
      __syncthreads();  // ABCD visible; previous MAC done before overwriting sW
      // ---- stage sW[64][48] for m in [mb*64, mb*64+64) ----
      {
        const int pgrp = t / 96, tf = t % 96;
#pragma unroll
        for (int pp = 0; pp < 2; ++pp) {
          const int p = pp * 4 + pgrp;
          const float* src = tensors +
              ((size_t)((c * 8 + p) * 961 + site) * 256 + mb * 64) * 6 + tf * 4;
          const float4 vv4 = *(const float4*)src;
          const float vv[4] = {vv4.x, vv4.y, vv4.z, vv4.w};
          const int f = tf * 4;
#pragma unroll
          for (int u2 = 0; u2 < 4; ++u2) {
            const int f2 = f + u2;                // = m_local*6 + o
            sW[(f2 / 6) * 48 + p * 6 + (f2 % 6)] = vv[u2];
          }
        }
      }
      __syncthreads();

      // ---- MAC: 64 m = 4 ij x 16 kl ----
#pragma unroll
      for (int klq = 0; klq < 4; ++klq) {
        float4 cd4[4];
#pragma unroll
        for (int r = 0; r < 4; ++r)
          cd4[r] = *(const float4*)&sCD[(ng * 4 + r) * 16 + klq * 4];
#pragma unroll
        for (int ij4 = 0; ij4 < 4; ++ij4) {
          float abv[4];
#pragma unroll
          for (int r = 0; r < 4; ++r)
            abv[r] = sAB[(ng * 4 + r) * 16 + mb * 4 + ij4];
          float4 w4[4];
#pragma unroll
          for (int s = 0; s < 4; ++s)
            w4[s] = *(const float4*)&sW[(ij4 * 16 + klq * 4 + s) * 48 + pog * 4];
#pragma unroll
          for (int r = 0; r < 4; ++r) {
            const float cdr[4] = {cd4[r].x, cd4[r].y, cd4[r].z, cd4[r].w};
#pragma unroll
            for (int s = 0; s < 4; ++s) {
              const float A = abv[r] * cdr[s];
              acc[r][0] = fmaf(A, w4[s].x, acc[r][0]);
              acc[r][1] = fmaf(A, w4[s].y, acc[r][1]);
              acc[r][2] = fmaf(A, w4[s].z, acc[r][2]);
              acc[r][3] = fmaf(A, w4[s].w, acc[r][3]);
            }
          }
        }
      }
    }
  }

  if (TO_WS) {
    // ws[site][f], f = n*48 + po. 12 lanes x float4 = 192 contiguous bytes.
#pragma unroll
    for (int r = 0; r < 4; ++r) {
      float4 v = make_float4(acc[r][0], acc[r][1], acc[r][2], acc[r][3]);
      *(float4*)&dst[(size_t)site * 6144 + (ng * 4 + r) * 48 + pog * 4] = v;
    }
  } else {
    // fallback: direct scattered stores with bias (slow path)
#pragma unroll
    for (int q = 0; q < 4; ++q) {
      const int po = pog * 4 + q;
      const int p = po / 6, o = po % 6;
      const float bq = bias[(p * 961 + site) * 6 + o];
#pragma unroll
      for (int r = 0; r < 4; ++r) {
        const int f = (ng * 4 + r) * 48 + po;
        dst[(size_t)f * 961 + site] = acc[r][q] + bq;
      }
    }
  }
}

// out[f*961 + site] = ws[site*6144 + f] + bias[(p*961+site)*6 + o]
__global__ __launch_bounds__(256, 8)
void ttn_transpose_bias(const float* __restrict__ ws,
                        const float* __restrict__ bias,
                        float* __restrict__ out) {
  __shared__ float tile[32][33];
  const int f0 = blockIdx.x * 32;
  const int s0 = blockIdx.y * 32;
  const int tx = threadIdx.x;       // 0..31
  const int ty = threadIdx.y;       // 0..7

#pragma unroll
  for (int rr = 0; rr < 4; ++rr) {
    const int srow = ty + rr * 8;
    const int site = s0 + srow;
    if (site < 961)
      tile[srow][tx] = ws[(size_t)site * 6144 + f0 + tx];
  }
  __syncthreads();

#pragma unroll
  for (int rr = 0; rr < 4; ++rr) {
    const int fy = ty + rr * 8;
    const int f = f0 + fy;
    const int site = s0 + tx;
    if (site < 961) {
      const int po = f % 48;
      const int p = po / 6, o = po - p * 6;
      out[(size_t)f * 961 + site] = tile[tx][fy] + bias[(p * 961 + site) * 6 + o];
    }
  }
}

extern "C" void kernel_launch(void* const* d_in, const int* in_sizes, int n_in,
                              void* d_out, int out_size, void* d_ws, size_t ws_size,
                              hipStream_t stream) {
  const float* x       = (const float*)d_in[0];
  const float* tensors = (const float*)d_in[1];
  const float* bias    = (const float*)d_in[2];
  float* out           = (float*)d_out;

  const size_t need = (size_t)WS_ELEMS * sizeof(float);
  if (d_ws != nullptr && ws_size >= need) {
    float* ws = (float*)d_ws;
    hipLaunchKernelGGL((ttn_conv_fp32<true>), dim3(961), dim3(384), 0, stream,
                       x, tensors, bias, ws);
    hipLaunchKernelGGL(ttn_transpose_bias, dim3(192, 31), dim3(32, 8), 0, stream,
                       ws, bias, out);
  } else {
    hipLaunchKernelGGL((ttn_conv_fp32<false>), dim3(961), dim3(384), 0, stream,
                       x, tensors, bias, out);
  }
}

// Round 3
// 244.774 us; speedup vs baseline: 19.5774x; 19.5774x over previous
//
#include <hip/hip_runtime.h>

// TTN Conv: out[n,p,o,site] = sum_{c,i,j,k,l} a_i b_j c_k d_l * W[c,p,site,ijkl,o] + bias
// Per site: GEMM D[n=128][po=48] = sum_k A[n][k=768] * W[k][po], bf16 MFMA 16x16x32.
//
// x:       (128, 3, 4, 32, 32) fp32
// tensors: (3, 8, 31, 31, 256, 6) fp32  -> per (c,p,site): [m=256][o=6] contiguous
// bias:    (8, 31, 31, 6) fp32
// out:     (128, 8, 6, 31, 31) fp32 = out[f*961 + site], f = n*48 + p*6 + o
//
// Phase 1 (1 block/site, 256 thr = 4 waves): K in 12 chunks of 64 (c x mb).
//   sA[128][64] bf16 (stride 72): A[n][ij4*16+kl] = a_mb*b_j * c_k*d_l, built from regs.
//   sW[48][64] bf16 (stride 72):  sW[p*6+o][m] transposed from global, packed b32 writes.
//   W prefetched one chunk ahead in regs. Wave w: n in [w*32,w*32+32), 2x3 MFMA tiles.
//   Epilogue -> ws[site][n*48+po]: each store instr covers 4 full 64B lines.
// Phase 2: tiled transpose ws(961 x 6144) -> out(6144 x 961) + bias (proven in R2).
//
// Stride 72 = 64+8: row shift of one 16B granule -> even granule spread on all
// b128 LDS ops (16 rows x shift-1 over 8 groups = 2-way, free per m136).
// launch_bounds(256,4): VGPR cap 128 vs ~100 needed -- R2's spill (cap 85) avoided.

typedef __attribute__((ext_vector_type(8))) short short8;
typedef __attribute__((ext_vector_type(4))) float floatx4;
typedef __attribute__((ext_vector_type(4))) unsigned int uintx4;

#define WS_ELEMS (961u * 6144u)
#define SA_STR 72
#define SW_STR 72

static __device__ __forceinline__ unsigned short f2bf(float f) {
  union { float f; unsigned u; } v; v.f = f;
  unsigned r = v.u + 0x7FFFu + ((v.u >> 16) & 1u);   // RNE to bf16
  return (unsigned short)(r >> 16);
}

template <bool TO_WS>
__global__ __launch_bounds__(256, 4)
void ttn_conv_mfma(const float* __restrict__ x,
                   const float* __restrict__ tensors,
                   const float* __restrict__ bias,
                   float* __restrict__ dst) {
  __shared__ __align__(16) unsigned short sA[128 * SA_STR];  // 18432 B
  __shared__ __align__(16) unsigned short sW[48 * SW_STR];   //  6912 B

  const int site = blockIdx.x;
  const int xx = site / 31, yy = site - xx * 31;
  const int t = threadIdx.x;
  const int lane = t & 63, wave = t >> 6;
  const int row = lane & 15, quad = lane >> 4;

  const int n_st = t & 127;   // sA staging: this thread's n
  const int h = t >> 7;       // sA staging: ij4 in {2h, 2h+1}  (j = 2h+e, i = mb)
  const int p_st = t >> 5;    // sW staging: p (0..7)
  const int q_st = t & 31;    // sW staging: m-pair index (m = 2q, 2q+1)

  floatx4 acc[2][3];
#pragma unroll
  for (int i0 = 0; i0 < 2; ++i0)
#pragma unroll
    for (int j0 = 0; j0 < 3; ++j0)
      acc[i0][j0] = (floatx4){0.f, 0.f, 0.f, 0.f};

  float areg[4], b0 = 0.f, b1 = 0.f, cdreg[16];
  float4 wv0, wv1, wv2;

  // prefetch W chunk 0 (c=0, mb=0)
  {
    const float* src = tensors + ((size_t)(p_st * 961 + site)) * 1536 + 12 * q_st;
    wv0 = *(const float4*)src;
    wv1 = *(const float4*)(src + 4);
    wv2 = *(const float4*)(src + 8);
  }

#pragma unroll
  for (int ch = 0; ch < 12; ++ch) {
    const int mb = ch & 3;
    if ((ch & 3) == 0) {
      const int c = ch >> 2;
      // load x factors for this c (scalar loads: 4B-aligned only)
      const float* xp = x + ((size_t)n_st * 3 + c) * 4096 + xx * 32 + yy;
      float bq[4], cq[4], dq[4];
#pragma unroll
      for (int i = 0; i < 4; ++i) {
        const float* r0 = xp + i * 1024;
        areg[i] = r0[0];   // a_i = x[n,c,i,xx,  yy  ]
        cq[i]   = r0[1];   // c_i = x[n,c,i,xx,  yy+1]
        bq[i]   = r0[32];  // b_i = x[n,c,i,xx+1,yy  ]
        dq[i]   = r0[33];  // d_i = x[n,c,i,xx+1,yy+1]
      }
      b0 = h ? bq[2] : bq[0];
      b1 = h ? bq[3] : bq[1];
#pragma unroll
      for (int k2 = 0; k2 < 4; ++k2)
#pragma unroll
        for (int l2 = 0; l2 < 4; ++l2)
          cdreg[k2 * 4 + l2] = cq[k2] * dq[l2];
    }
    __syncthreads();  // prev chunk's frag reads done before overwrite

    // ---- stage sW[po][m_local] from prefetched regs (12 floats = m pair x 6 o) ----
    {
      const float vv[12] = {wv0.x, wv0.y, wv0.z, wv0.w, wv1.x, wv1.y,
                            wv1.z, wv1.w, wv2.x, wv2.y, wv2.z, wv2.w};
#pragma unroll
      for (int o = 0; o < 6; ++o) {
        const unsigned pk = (unsigned)f2bf(vv[o]) | ((unsigned)f2bf(vv[o + 6]) << 16);
        *(unsigned*)&sW[(p_st * 6 + o) * SW_STR + 2 * q_st] = pk;
      }
    }
    // ---- stage sA[n][ij4*16+kl] = (a_mb * b_{2h+e}) * cd[kl] ----
#pragma unroll
    for (int e = 0; e < 2; ++e) {
      const float ab = areg[mb] * (e ? b1 : b0);
      unsigned pk[8];
#pragma unroll
      for (int u = 0; u < 8; ++u)
        pk[u] = (unsigned)f2bf(ab * cdreg[2 * u]) |
                ((unsigned)f2bf(ab * cdreg[2 * u + 1]) << 16);
      uintx4* dp = (uintx4*)&sA[n_st * SA_STR + (2 * h + e) * 16];
      uintx4 v0 = {pk[0], pk[1], pk[2], pk[3]};
      uintx4 v1 = {pk[4], pk[5], pk[6], pk[7]};
      dp[0] = v0;
      dp[1] = v1;
    }
    // ---- prefetch next chunk's W (hidden under MFMA below) ----
    if (ch < 11) {
      const int cn = (ch + 1) >> 2, mbn = (ch + 1) & 3;
      const float* src = tensors +
          ((size_t)((cn * 8 + p_st) * 961 + site)) * 1536 + (mbn * 64 + 2 * q_st) * 6;
      wv0 = *(const float4*)src;
      wv1 = *(const float4*)(src + 4);
      wv2 = *(const float4*)(src + 8);
    }
    __syncthreads();

    // ---- MFMA: 2 K-steps of 32, wave tile 2(M) x 3(N) ----
#pragma unroll
    for (int ks = 0; ks < 2; ++ks) {
      const int kof = ks * 32 + quad * 8;
      short8 af[2], bf[3];
#pragma unroll
      for (int mt = 0; mt < 2; ++mt)
        af[mt] = *(const short8*)&sA[(wave * 32 + mt * 16 + row) * SA_STR + kof];
#pragma unroll
      for (int nt = 0; nt < 3; ++nt)
        bf[nt] = *(const short8*)&sW[(nt * 16 + row) * SW_STR + kof];
#pragma unroll
      for (int mt = 0; mt < 2; ++mt)
#pragma unroll
        for (int nt = 0; nt < 3; ++nt)
          acc[mt][nt] = __builtin_amdgcn_mfma_f32_16x16x32_bf16(
              af[mt], bf[nt], acc[mt][nt], 0, 0, 0);
    }
  }

  // ---- epilogue: D row = quad*4+r (n-local), col = lane&15 (po-local) ----
  if (TO_WS) {
#pragma unroll
    for (int mt = 0; mt < 2; ++mt)
#pragma unroll
      for (int r = 0; r < 4; ++r) {
        const int n = wave * 32 + mt * 16 + quad * 4 + r;
#pragma unroll
        for (int nt = 0; nt < 3; ++nt) {
          const int po = nt * 16 + row;
          dst[(size_t)site * 6144 + n * 48 + po] = acc[mt][nt][r];
        }
      }
  } else {
#pragma unroll
    for (int mt = 0; mt < 2; ++mt)
#pragma unroll
      for (int r = 0; r < 4; ++r) {
        const int n = wave * 32 + mt * 16 + quad * 4 + r;
#pragma unroll
        for (int nt = 0; nt < 3; ++nt) {
          const int po = nt * 16 + row;
          const int p = po / 6, o = po - p * 6;
          dst[(size_t)(n * 48 + po) * 961 + site] =
              acc[mt][nt][r] + bias[(p * 961 + site) * 6 + o];
        }
      }
  }
}

// out[f*961 + site] = ws[site*6144 + f] + bias[(p*961+site)*6 + o],  f = n*48+p*6+o
__global__ __launch_bounds__(256, 8)
void ttn_transpose_bias(const float* __restrict__ ws,
                        const float* __restrict__ bias,
                        float* __restrict__ out) {
  __shared__ float tile[32][33];
  const int f0 = blockIdx.x * 32;
  const int s0 = blockIdx.y * 32;
  const int tx = threadIdx.x;       // 0..31
  const int ty = threadIdx.y;       // 0..7

#pragma unroll
  for (int rr = 0; rr < 4; ++rr) {
    const int srow = ty + rr * 8;
    const int site = s0 + srow;
    if (site < 961)
      tile[srow][tx] = ws[(size_t)site * 6144 + f0 + tx];
  }
  __syncthreads();

#pragma unroll
  for (int rr = 0; rr < 4; ++rr) {
    const int fy = ty + rr * 8;
    const int f = f0 + fy;
    const int site = s0 + tx;
    if (site < 961) {
      const int po = f % 48;
      const int p = po / 6, o = po - p * 6;
      out[(size_t)f * 961 + site] = tile[tx][fy] + bias[(p * 961 + site) * 6 + o];
    }
  }
}

extern "C" void kernel_launch(void* const* d_in, const int* in_sizes, int n_in,
                              void* d_out, int out_size, void* d_ws, size_t ws_size,
                              hipStream_t stream) {
  const float* x       = (const float*)d_in[0];
  const float* tensors = (const float*)d_in[1];
  const float* bias    = (const float*)d_in[2];
  float* out           = (float*)d_out;

  const size_t need = (size_t)WS_ELEMS * sizeof(float);
  if (d_ws != nullptr && ws_size >= need) {
    float* ws = (float*)d_ws;
    hipLaunchKernelGGL((ttn_conv_mfma<true>), dim3(961), dim3(256), 0, stream,
                       x, tensors, bias, ws);
    hipLaunchKernelGGL(ttn_transpose_bias, dim3(192, 31), dim3(32, 8), 0, stream,
                       ws, bias, out);
  } else {
    hipLaunchKernelGGL((ttn_conv_mfma<false>), dim3(961), dim3(256), 0, stream,
                       x, tensors, bias, out);
  }
}